// Round 1
// baseline (168.483 us; speedup 1.0000x reference)
//
#include <hip/hip_runtime.h>

#define BH  64
#define SEQ 4096
#define DH  64

// ---------------------------------------------------------------------------
// Kernel 1: partial kv = k^T v over a chunk of S rows, one (b,h,chunk)/block.
// 128 threads. Thread tile: 4 d-values x 8 e-values (32 FMA / 3 ds_read_b128
// per staged row -> FMA-bound).
// ---------------------------------------------------------------------------
__global__ __launch_bounds__(128) void kv_partial_kernel(
    const float* __restrict__ k, const float* __restrict__ v,
    float* __restrict__ partial, int nchunk, int rows_per_chunk) {
  const int t = threadIdx.x;
  const int bh = blockIdx.x / nchunk;
  const int chunk = blockIdx.x - bh * nchunk;

  const float* kb = k + (size_t)bh * SEQ * DH + (size_t)chunk * rows_per_chunk * DH;
  const float* vb = v + (size_t)bh * SEQ * DH + (size_t)chunk * rows_per_chunk * DH;

  __shared__ float ks[32 * 64];
  __shared__ float vs[32 * 64];

  const int td = t & 15;     // d-group: d0 = td*4
  const int te = t >> 4;     // e-group: e0 = te*8  (0..7)
  const int d0 = td * 4;
  const int e0 = te * 8;

  float acc[4][8];
#pragma unroll
  for (int i = 0; i < 4; ++i)
#pragma unroll
    for (int j = 0; j < 8; ++j) acc[i][j] = 0.f;

  for (int t0 = 0; t0 < rows_per_chunk; t0 += 32) {
    // stage 32 rows of k and v (2048 floats each) via float4, coalesced
    const float4* gk4 = (const float4*)(kb + (size_t)t0 * DH);
    const float4* gv4 = (const float4*)(vb + (size_t)t0 * DH);
    float4* ks4 = (float4*)ks;
    float4* vs4 = (float4*)vs;
#pragma unroll
    for (int j = 0; j < 4; ++j) {
      ks4[t + j * 128] = gk4[t + j * 128];
      vs4[t + j * 128] = gv4[t + j * 128];
    }
    __syncthreads();

#pragma unroll
    for (int r = 0; r < 32; ++r) {
      float4 a4  = *(const float4*)&ks[r * 64 + d0];
      float4 b04 = *(const float4*)&vs[r * 64 + e0];
      float4 b14 = *(const float4*)&vs[r * 64 + e0 + 4];
      float av[4] = {a4.x, a4.y, a4.z, a4.w};
      float bv[8] = {b04.x, b04.y, b04.z, b04.w, b14.x, b14.y, b14.z, b14.w};
#pragma unroll
      for (int i = 0; i < 4; ++i)
#pragma unroll
        for (int j = 0; j < 8; ++j) acc[i][j] += av[i] * bv[j];
    }
    __syncthreads();
  }

  float* pb = partial + (size_t)blockIdx.x * (DH * DH);
#pragma unroll
  for (int i = 0; i < 4; ++i) {
    float4 w0 = {acc[i][0], acc[i][1], acc[i][2], acc[i][3]};
    float4 w1 = {acc[i][4], acc[i][5], acc[i][6], acc[i][7]};
    *(float4*)&pb[(d0 + i) * 64 + e0]     = w0;
    *(float4*)&pb[(d0 + i) * 64 + e0 + 4] = w1;
  }
}

// ---------------------------------------------------------------------------
// Kernel 2: reduce partials -> final kv [BH][64*64]. Deterministic sum order.
// ---------------------------------------------------------------------------
__global__ __launch_bounds__(256) void kv_reduce_kernel(
    const float* __restrict__ partial, float* __restrict__ kvf, int nchunk) {
  const int bh = blockIdx.x;
  const int t = threadIdx.x;
#pragma unroll
  for (int j = 0; j < 16; ++j) {
    int idx = t + j * 256;
    float s = 0.f;
    for (int c = 0; c < nchunk; ++c)
      s += partial[((size_t)bh * nchunk + c) * (DH * DH) + idx];
    kvf[(size_t)bh * (DH * DH) + idx] = s;
  }
}

// ---------------------------------------------------------------------------
// Kernel 3: out = q @ kv.  Block: 128 rows x 64 cols, 256 threads.
// Thread tile: 8 rows (stride 16) x 4 cols. q staged in LDS with row pitch 68
// (16B-aligned rows; bank = (4r + d0)&31 with r in {tr,..,tr+? } -> lane rows
// tr in 0..3 per read -> 4 distinct banks, conflict-free).
// ---------------------------------------------------------------------------
__global__ __launch_bounds__(256) void out_kernel(
    const float* __restrict__ q, const float* __restrict__ kvf,
    float* __restrict__ out) {
  const int t = threadIdx.x;
  const int bh = blockIdx.x >> 5;
  const int rt = blockIdx.x & 31;
  const int s0 = rt * 128;

  __shared__ float q_lds[128 * 68];   // 34 KB, pitch 68 floats
  __shared__ float kv_lds[64 * 64];   // 16 KB

  // stage q tile (128x64) -> q_lds, pitched
  const float4* gq4 = (const float4*)(q + (size_t)bh * SEQ * DH + (size_t)s0 * DH);
#pragma unroll
  for (int j = 0; j < 8; ++j) {
    int fi = t + j * 256;            // 2048 float4 total
    float4 val = gq4[fi];
    int r = fi >> 4;
    int d0 = (fi & 15) * 4;
    *(float4*)&q_lds[r * 68 + d0] = val;
  }
  // stage kv (64x64) linear
  const float4* gkv4 = (const float4*)(kvf + (size_t)bh * (DH * DH));
  float4* kv4 = (float4*)kv_lds;
#pragma unroll
  for (int j = 0; j < 4; ++j) kv4[t + j * 256] = gkv4[t + j * 256];
  __syncthreads();

  const int tc = t & 15;   // col group: c0 = tc*4
  const int tr = t >> 4;   // row within 16-row stripe; rows = tr + 16*ri
  const int c0 = tc * 4;

  float acc[8][4];
#pragma unroll
  for (int i = 0; i < 8; ++i)
#pragma unroll
    for (int j = 0; j < 4; ++j) acc[i][j] = 0.f;

#pragma unroll
  for (int dstep = 0; dstep < 16; ++dstep) {
    const int d0 = dstep * 4;
    float4 kv0 = *(const float4*)&kv_lds[(d0 + 0) * 64 + c0];
    float4 kv1 = *(const float4*)&kv_lds[(d0 + 1) * 64 + c0];
    float4 kv2 = *(const float4*)&kv_lds[(d0 + 2) * 64 + c0];
    float4 kv3 = *(const float4*)&kv_lds[(d0 + 3) * 64 + c0];
#pragma unroll
    for (int ri = 0; ri < 8; ++ri) {
      const int r = tr + 16 * ri;
      float4 qv = *(const float4*)&q_lds[r * 68 + d0];
      acc[ri][0] += qv.x * kv0.x + qv.y * kv1.x + qv.z * kv2.x + qv.w * kv3.x;
      acc[ri][1] += qv.x * kv0.y + qv.y * kv1.y + qv.z * kv2.y + qv.w * kv3.y;
      acc[ri][2] += qv.x * kv0.z + qv.y * kv1.z + qv.z * kv2.z + qv.w * kv3.z;
      acc[ri][3] += qv.x * kv0.w + qv.y * kv1.w + qv.z * kv2.w + qv.w * kv3.w;
    }
  }

  float* ob = out + (size_t)bh * SEQ * DH;
#pragma unroll
  for (int ri = 0; ri < 8; ++ri) {
    int r = s0 + tr + 16 * ri;
    float4 w = {acc[ri][0], acc[ri][1], acc[ri][2], acc[ri][3]};
    *(float4*)&ob[r * 64 + c0] = w;
  }
}

// ---------------------------------------------------------------------------
extern "C" void kernel_launch(void* const* d_in, const int* in_sizes, int n_in,
                              void* d_out, int out_size, void* d_ws, size_t ws_size,
                              hipStream_t stream) {
  const float* q = (const float*)d_in[0];
  const float* k = (const float*)d_in[1];
  const float* v = (const float*)d_in[2];
  float* out = (float*)d_out;

  float* kvf = (float*)d_ws;                         // [BH][64*64] = 1 MB
  float* partial = kvf + (size_t)BH * DH * DH;       // [BH*nchunk][64*64]

  // pick nchunk (power of 2, <=16) based on available workspace
  int nchunk = 1;
  size_t used = (size_t)BH * DH * DH * sizeof(float);
  if (ws_size > used) {
    size_t slots = (ws_size - used) / ((size_t)BH * DH * DH * sizeof(float));
    while (nchunk * 2 <= 16 && (size_t)(nchunk * 2) <= slots) nchunk *= 2;
  }
  int rows = SEQ / nchunk;

  hipLaunchKernelGGL(kv_partial_kernel, dim3(BH * nchunk), dim3(128), 0, stream,
                     k, v, partial, nchunk, rows);
  hipLaunchKernelGGL(kv_reduce_kernel, dim3(BH), dim3(256), 0, stream,
                     partial, kvf, nchunk);
  hipLaunchKernelGGL(out_kernel, dim3(BH * 32), dim3(256), 0, stream,
                     q, kvf, out);
}

// Round 3
// 117.371 us; speedup vs baseline: 1.4355x; 1.4355x over previous
//
#include <hip/hip_runtime.h>

#define BH  64
#define SEQ 4096
#define DH  64

// ---------------------------------------------------------------------------
// Kernel 1: partial kv = k^T v over a chunk of S rows. One (b,h,chunk)/block.
// 256 threads = 4 waves. Thread tile 4(d) x 4(e); 16x16 thread grid covers
// the 64x64 output once. Per staged s-row: 2 ds_read_b128 + 16 FMA.
// LDS 16 KB, ~50 VGPR -> high occupancy.
// ---------------------------------------------------------------------------
__global__ __launch_bounds__(256) void kv_partial_kernel(
    const float* __restrict__ k, const float* __restrict__ v,
    float* __restrict__ partial, int nchunk, int rows_per_chunk) {
  const int t = threadIdx.x;
  const int bh = blockIdx.x / nchunk;
  const int chunk = blockIdx.x - bh * nchunk;

  const float* kb = k + (size_t)bh * SEQ * DH + (size_t)chunk * rows_per_chunk * DH;
  const float* vb = v + (size_t)bh * SEQ * DH + (size_t)chunk * rows_per_chunk * DH;

  __shared__ float ks[32 * 64];
  __shared__ float vs[32 * 64];

  const int d0 = (t & 15) * 4;   // 16 d-groups
  const int e0 = (t >> 4) * 4;   // 16 e-groups

  float acc[4][4];
#pragma unroll
  for (int i = 0; i < 4; ++i)
#pragma unroll
    for (int j = 0; j < 4; ++j) acc[i][j] = 0.f;

  for (int t0 = 0; t0 < rows_per_chunk; t0 += 32) {
    // stage 32 rows of k and v (8 KB each) via float4, fully coalesced
    const float4* gk4 = (const float4*)(kb + (size_t)t0 * DH);
    const float4* gv4 = (const float4*)(vb + (size_t)t0 * DH);
    float4* ks4 = (float4*)ks;
    float4* vs4 = (float4*)vs;
    ks4[t]       = gk4[t];
    ks4[t + 256] = gk4[t + 256];
    vs4[t]       = gv4[t];
    vs4[t + 256] = gv4[t + 256];
    __syncthreads();

#pragma unroll
    for (int r = 0; r < 32; ++r) {
      float4 kav = *(const float4*)&ks[r * 64 + d0];
      float4 vav = *(const float4*)&vs[r * 64 + e0];
      float ka[4] = {kav.x, kav.y, kav.z, kav.w};
      float va[4] = {vav.x, vav.y, vav.z, vav.w};
#pragma unroll
      for (int i = 0; i < 4; ++i)
#pragma unroll
        for (int j = 0; j < 4; ++j) acc[i][j] += ka[i] * va[j];
    }
    __syncthreads();
  }

  float* pb = partial + (size_t)blockIdx.x * (DH * DH);
#pragma unroll
  for (int i = 0; i < 4; ++i) {
    float4 w = {acc[i][0], acc[i][1], acc[i][2], acc[i][3]};
    *(float4*)&pb[(d0 + i) * 64 + e0] = w;
  }
}

// ---------------------------------------------------------------------------
// Kernel 2: reduce partials -> kvf [BH][64*64]. Fully coalesced float4.
// Grid MUST cover 65536 float4 slots: 256 blocks x 256 threads.
// ---------------------------------------------------------------------------
__global__ __launch_bounds__(256) void kv_reduce_kernel(
    const float* __restrict__ partial, float* __restrict__ kvf, int nchunk) {
  const int gid = blockIdx.x * 256 + threadIdx.x;   // 65536 float4 slots
  const int bh = gid >> 10;                          // 1024 float4 per head
  const int idx = gid & 1023;
  float4 s = {0.f, 0.f, 0.f, 0.f};
  for (int c = 0; c < nchunk; ++c) {
    const float4* p = (const float4*)(partial + ((size_t)bh * nchunk + c) * (DH * DH));
    float4 x = p[idx];
    s.x += x.x; s.y += x.y; s.z += x.z; s.w += x.w;
  }
  ((float4*)kvf)[gid] = s;
}

// ---------------------------------------------------------------------------
// Kernel 3: out = q @ kv. No LDS. Thread = 1 q-row x 16 cols.
// Col-group = wave id (readfirstlane -> uniform) so kv row chunks are
// wave-uniform loads (L2-resident 1 MB total). q row held in registers.
// ---------------------------------------------------------------------------
__global__ __launch_bounds__(256) void out_kernel(
    const float* __restrict__ q, const float* __restrict__ kvf,
    float* __restrict__ out) {
  const int t = threadIdx.x;
  const int bh = blockIdx.x >> 6;        // 64 row-blocks per head
  const int rb = blockIdx.x & 63;
  const int row = rb * 64 + (t & 63);
  const int cg = __builtin_amdgcn_readfirstlane(t >> 6);  // wave id, uniform
  const int c0 = cg * 16;

  const float* qrow = q + (size_t)bh * SEQ * DH + (size_t)row * DH;
  const float* kvb = kvf + (size_t)bh * (DH * DH) + c0;

  float acc[16];
#pragma unroll
  for (int j = 0; j < 16; ++j) acc[j] = 0.f;

#pragma unroll
  for (int half = 0; half < 2; ++half) {
    // load 32 q values for this half into registers
    float qr[32];
    const float4* q4 = (const float4*)(qrow + half * 32);
#pragma unroll
    for (int i = 0; i < 8; ++i) {
      float4 tmp = q4[i];
      qr[4 * i + 0] = tmp.x;
      qr[4 * i + 1] = tmp.y;
      qr[4 * i + 2] = tmp.z;
      qr[4 * i + 3] = tmp.w;
    }
    const float* kvh = kvb + (size_t)half * 32 * DH;
#pragma unroll
    for (int dd = 0; dd < 32; ++dd) {
      const float qs = qr[dd];
      const float4* kr = (const float4*)(kvh + (size_t)dd * DH);
      float4 k0 = kr[0];
      float4 k1 = kr[1];
      float4 k2 = kr[2];
      float4 k3 = kr[3];
      acc[0]  += qs * k0.x; acc[1]  += qs * k0.y; acc[2]  += qs * k0.z; acc[3]  += qs * k0.w;
      acc[4]  += qs * k1.x; acc[5]  += qs * k1.y; acc[6]  += qs * k1.z; acc[7]  += qs * k1.w;
      acc[8]  += qs * k2.x; acc[9]  += qs * k2.y; acc[10] += qs * k2.z; acc[11] += qs * k2.w;
      acc[12] += qs * k3.x; acc[13] += qs * k3.y; acc[14] += qs * k3.z; acc[15] += qs * k3.w;
    }
  }

  float* orow = out + (size_t)bh * SEQ * DH + (size_t)row * DH + c0;
#pragma unroll
  for (int j = 0; j < 4; ++j) {
    float4 w = {acc[4 * j + 0], acc[4 * j + 1], acc[4 * j + 2], acc[4 * j + 3]};
    *(float4*)&orow[4 * j] = w;
  }
}

// ---------------------------------------------------------------------------
extern "C" void kernel_launch(void* const* d_in, const int* in_sizes, int n_in,
                              void* d_out, int out_size, void* d_ws, size_t ws_size,
                              hipStream_t stream) {
  const float* q = (const float*)d_in[0];
  const float* k = (const float*)d_in[1];
  const float* v = (const float*)d_in[2];
  float* out = (float*)d_out;

  float* kvf = (float*)d_ws;                      // [BH][64*64] = 1 MB
  float* partial = kvf + (size_t)BH * DH * DH;    // [BH*nchunk][64*64]

  // largest power-of-2 nchunk <= 32 that fits in workspace
  int nchunk = 32;
  const size_t head_mat = (size_t)BH * DH * DH * sizeof(float);  // 1 MB
  while (nchunk > 1 && ws_size < head_mat * (size_t)(nchunk + 1)) nchunk >>= 1;
  int rows = SEQ / nchunk;

  hipLaunchKernelGGL(kv_partial_kernel, dim3(BH * nchunk), dim3(256), 0, stream,
                     k, v, partial, nchunk, rows);
  // 65536 float4 slots -> 256 blocks x 256 threads
  hipLaunchKernelGGL(kv_reduce_kernel, dim3(256), dim3(256), 0, stream,
                     partial, kvf, nchunk);
  hipLaunchKernelGGL(out_kernel, dim3(BH * 64), dim3(256), 0, stream,
                     q, kvf, out);
}